// Round 13
// baseline (201.003 us; speedup 1.0000x reference)
//
#include <hip/hip_runtime.h>

#define D 128
#define CAP 64      // per-node bucket capacity (max degree ~35 for Poisson(12))
#define NBLK_A 128  // binA partition blocks
#define SUBCAP 64   // per-(block,bin) segment capacity (lambda=24, +8 sigma)
#define BSTR 66     // LDS bucket stride (ushorts), padded to break bank conflicts
#define BINSHIFT 8  // 256 nodes per bin

typedef __bf16 bf16x8 __attribute__((ext_vector_type(8)));
typedef float f32x4 __attribute__((ext_vector_type(4)));

static __device__ __forceinline__ unsigned short f2bf(float x) {
    unsigned int u = __builtin_bit_cast(unsigned int, x);
    unsigned int r = u + 0x7fffu + ((u >> 16) & 1u);
    return (unsigned short)(r >> 16);
}
static __device__ __forceinline__ float bitf(unsigned int u) {
    return __builtin_bit_cast(float, u);
}

// software grid barrier (proven R5-R7)
static __device__ __forceinline__ void gbar(unsigned int* ctr, unsigned int target) {
    __syncthreads();
    if (threadIdx.x == 0) {
        __threadfence();
        __hip_atomic_fetch_add(ctr, 1u, __ATOMIC_ACQ_REL, __HIP_MEMORY_SCOPE_AGENT);
        while (__hip_atomic_load(ctr, __ATOMIC_ACQUIRE, __HIP_MEMORY_SCOPE_AGENT) < target) {
            __builtin_amdgcn_s_sleep(16);
        }
        __threadfence();
    }
    __syncthreads();
}

// ---------------- K1: binA partition (blocks 0..127) || MFMA gemm w/ self-transpose ----------------
__global__ __launch_bounds__(256) void k1_kernel(const int* __restrict__ ei,
                                                 const float* __restrict__ W,
                                                 const float* __restrict__ x,
                                                 unsigned int* __restrict__ counts,
                                                 unsigned int* __restrict__ binned,
                                                 unsigned int* __restrict__ ctrs,
                                                 unsigned short* __restrict__ hs, int n, int E) {
    __shared__ char smem[48 * 1024];
    int t = threadIdx.x;
    int bid = blockIdx.x;
    if (bid == 0 && t < 8) ctrs[t] = 0u;

    if (bid < NBLK_A) {
        // ---- binA: partition edges into dst-bins (packed dst<<16|src) ----
        unsigned int* hist = (unsigned int*)smem;
        hist[t] = 0u;
        __syncthreads();
        int chunk = (E + NBLK_A - 1) / NBLK_A;
        int s0 = bid * chunk, s1 = min(E, s0 + chunk);
        const int* dstp = ei + E;
        for (int e = s0 + t; e < s1; e += 256) atomicAdd(&hist[dstp[e] >> BINSHIFT], 1u);
        __syncthreads();
        counts[bid * 256 + t] = hist[t];
        __syncthreads();
        hist[t] = 0u;
        __syncthreads();
        for (int e = s0 + t; e < s1; e += 256) {
            int src = ei[e];
            int d = dstp[e];
            int bin = d >> BINSHIFT;
            unsigned int off = atomicAdd(&hist[bin], 1u);
            binned[((unsigned)bin * NBLK_A + (unsigned)bid) * SUBCAP + off] =
                ((unsigned)d << 16) | (unsigned)src;
        }
        return;
    }

    // ---- MFMA gemm: hs = bf16(X*W), unscaled; W transposed+cast in-block ----
    uint4* Xs = (uint4*)smem;         // 64*16  = 16 KB
    uint4* Ws = (uint4*)smem + 1024;  // 128*16 = 32 KB
    int rowbase = (bid - NBLK_A) * 64;

    for (int cell = t; cell < 2048; cell += 256) {
        int nc = cell >> 4, s = cell & 15;
        const float* col = W + (s * 8) * 128 + nc;
        unsigned int a0 = f2bf(col[0]) | ((unsigned)f2bf(col[128]) << 16);
        unsigned int a1 = f2bf(col[256]) | ((unsigned)f2bf(col[384]) << 16);
        unsigned int a2 = f2bf(col[512]) | ((unsigned)f2bf(col[640]) << 16);
        unsigned int a3 = f2bf(col[768]) | ((unsigned)f2bf(col[896]) << 16);
        Ws[nc * 16 + (s ^ (nc & 7))] = make_uint4(a0, a1, a2, a3);
    }
    const float4* x4 = (const float4*)x;
#pragma unroll
    for (int j = 0; j < 4; ++j) {
        int gi = t + j * 256;
        int r = gi >> 4, s = gi & 15;
        uint4 v = make_uint4(0u, 0u, 0u, 0u);
        int grow = rowbase + r;
        if (grow < n) {
            float4 f0 = x4[(size_t)grow * 32 + s * 2];
            float4 f1 = x4[(size_t)grow * 32 + s * 2 + 1];
            v.x = f2bf(f0.x) | ((unsigned)f2bf(f0.y) << 16);
            v.y = f2bf(f0.z) | ((unsigned)f2bf(f0.w) << 16);
            v.z = f2bf(f1.x) | ((unsigned)f2bf(f1.y) << 16);
            v.w = f2bf(f1.z) | ((unsigned)f2bf(f1.w) << 16);
        }
        Xs[r * 16 + (s ^ (r & 7))] = v;
    }
    __syncthreads();

    int w = t >> 6, l = t & 63;
    int lr = l & 15, lg = l >> 4;
    f32x4 acc[4][2] = {};

#pragma unroll
    for (int kt = 0; kt < 4; ++kt) {
        int ks = kt * 4 + lg;
        bf16x8 bfr[2];
#pragma unroll
        for (int ct = 0; ct < 2; ++ct) {
            int nc = w * 32 + ct * 16 + lr;
            bfr[ct] = __builtin_bit_cast(bf16x8, Ws[nc * 16 + (ks ^ (nc & 7))]);
        }
#pragma unroll
        for (int mt = 0; mt < 4; ++mt) {
            int mr = mt * 16 + lr;
            bf16x8 afr = __builtin_bit_cast(bf16x8, Xs[mr * 16 + (ks ^ (mr & 7))]);
            acc[mt][0] = __builtin_amdgcn_mfma_f32_16x16x32_bf16(afr, bfr[0], acc[mt][0], 0, 0, 0);
            acc[mt][1] = __builtin_amdgcn_mfma_f32_16x16x32_bf16(afr, bfr[1], acc[mt][1], 0, 0, 0);
        }
    }

#pragma unroll
    for (int mt = 0; mt < 4; ++mt) {
        int row0 = rowbase + mt * 16 + lg * 4;
#pragma unroll
        for (int r = 0; r < 4; ++r) {
            int grow = row0 + r;
            if (grow < n) {
#pragma unroll
                for (int ct = 0; ct < 2; ++ct) {
                    int col = w * 32 + ct * 16 + lr;
                    hs[(size_t)grow * 128 + col] = f2bf(acc[mt][ct][r]);
                }
            }
        }
    }
}

#define ACC8F(A0, A1, U, DS)                    \
    do {                                        \
        A0.x += bitf((U).x << 16) * DS;         \
        A0.y += bitf((U).x & 0xffff0000u) * DS; \
        A0.z += bitf((U).y << 16) * DS;         \
        A0.w += bitf((U).y & 0xffff0000u) * DS; \
        A1.x += bitf((U).z << 16) * DS;         \
        A1.y += bitf((U).z & 0xffff0000u) * DS; \
        A1.z += bitf((U).w << 16) * DS;         \
        A1.w += bitf((U).w & 0xffff0000u) * DS; \
    } while (0)

// ---------------- K3: binB (LDS bucket) + disf + 4-column-pass gather ----------------
// One block per bin: 1024 thr = 256 nodes x 4 lanes; bucket lives in LDS only.
__global__ __launch_bounds__(1024) void k3_kernel(const unsigned int* __restrict__ counts,
                                                  const unsigned int* __restrict__ binned,
                                                  float* __restrict__ disf,
                                                  const unsigned short* __restrict__ hs,
                                                  const float* __restrict__ bias,
                                                  unsigned int* __restrict__ ctrs,
                                                  float* __restrict__ out, int n, int NB) {
    __shared__ unsigned short sbucket[256 * BSTR];  // 33 KB
    __shared__ unsigned int lcnt[256];
    int t = threadIdx.x;
    int b = blockIdx.x;

    if (t < 256) lcnt[t] = 0u;
    __syncthreads();

    // phase 1: bucketize this bin's edges into LDS
    int wv = t >> 6, ln = t & 63;
    for (int k = wv; k < NBLK_A; k += 16) {
        int m = (int)counts[k * 256 + b];
        unsigned int base = ((unsigned)b * NBLK_A + (unsigned)k) * SUBCAP;
        for (int i = ln; i < m; i += 64) {
            unsigned int p = binned[base + i];
            unsigned int d = p >> 16;
            unsigned int src = p & 0xffffu;
            unsigned int slot = atomicAdd(&lcnt[d & 255u], 1u);
            sbucket[(d & 255u) * BSTR + (slot & (CAP - 1))] = (unsigned short)src;
        }
    }
    __syncthreads();

    // publish disf for this bin (needed globally by all other blocks)
    if (t < 256) {
        int nd = (b << BINSHIFT) + t;
        if (nd < n) disf[nd] = rsqrtf((float)lcnt[t] + 1.0f);
    }
    gbar(&ctrs[0], (unsigned)NB);  // correctness: all disf visible before gather

    int local = t >> 2, l = t & 3;
    int node = (b << BINSHIFT) + local;
    bool valid = node < n;
    unsigned int c = valid ? lcnt[local] : 0u;
    float dn = rsqrtf((float)c + 1.0f);
    const unsigned short* sb = &sbucket[local * BSTR];

    for (int p = 0; p < 4; ++p) {
        if (valid) {
            int coff = p * 32 + l * 8;  // column offset (8 bf16 per lane)
            uint4 u = *(const uint4*)(hs + ((size_t)node << 7) + coff);  // self
            float4 a0 = make_float4(bitf(u.x << 16) * dn, bitf(u.x & 0xffff0000u) * dn,
                                    bitf(u.y << 16) * dn, bitf(u.y & 0xffff0000u) * dn);
            float4 a1 = make_float4(bitf(u.z << 16) * dn, bitf(u.z & 0xffff0000u) * dn,
                                    bitf(u.w << 16) * dn, bitf(u.w & 0xffff0000u) * dn);
#pragma unroll 4
            for (int j = 0; j < (int)c; ++j) {
                int s = (int)sb[j];            // LDS broadcast across the 4 lanes
                float ds = disf[s];
                uint4 uu = *(const uint4*)(hs + ((size_t)s << 7) + coff);
                ACC8F(a0, a1, uu, ds);
            }
            float4 bv0 = *(const float4*)(bias + coff);
            float4 bv1 = *(const float4*)(bias + coff + 4);
            float4 r0 = make_float4(a0.x * dn + bv0.x, a0.y * dn + bv0.y, a0.z * dn + bv0.z,
                                    a0.w * dn + bv0.w);
            float4 r1 = make_float4(a1.x * dn + bv1.x, a1.y * dn + bv1.y, a1.z * dn + bv1.z,
                                    a1.w * dn + bv1.w);
            *(float4*)(out + ((size_t)node << 7) + coff) = r0;
            *(float4*)(out + ((size_t)node << 7) + coff + 4) = r1;
        }
        if (p < 3) gbar(&ctrs[1 + p], (unsigned)NB);  // locality alignment (optional)
    }
}

extern "C" void kernel_launch(void* const* d_in, const int* in_sizes, int n_in,
                              void* d_out, int out_size, void* d_ws, size_t ws_size,
                              hipStream_t stream) {
    const float* x = (const float*)d_in[0];
    const int* ei = (const int*)d_in[1];  // [2, E] int32
    const float* W = (const float*)d_in[2];
    const float* b = (const float*)d_in[3];
    float* out = (float*)d_out;

    int n = in_sizes[0] / D;  // 50000
    int E = in_sizes[1] / 2;  // 600000
    int NB = (n + 255) >> 8;  // 196 bins of 256 nodes

    unsigned int* counts = (unsigned int*)d_ws;                 // NBLK_A*256
    unsigned int* ctrs = counts + NBLK_A * 256;                 // 8
    float* disf = (float*)(ctrs + 8);                           // n
    unsigned int* binned = (unsigned int*)(disf + n);           // NB*NBLK_A*SUBCAP
    unsigned short* hs = (unsigned short*)(binned + (size_t)NB * NBLK_A * SUBCAP);  // n*D

    k1_kernel<<<NBLK_A + (n + 63) / 64, 256, 0, stream>>>(ei, W, x, counts, binned, ctrs, hs, n,
                                                          E);
    k3_kernel<<<NB, 1024, 0, stream>>>(counts, binned, disf, hs, b, ctrs, out, n, NB);
}

// Round 14
// 94.302 us; speedup vs baseline: 2.1315x; 2.1315x over previous
//
#include <hip/hip_runtime.h>

#define D 128
#define CAP 64      // per-node bucket capacity (max degree ~35 for Poisson(12))
#define NBLK_A 128  // binA partition blocks
#define SUBCAP 64   // per-(block,bin) segment capacity (lambda=24, +8 sigma)
#define BINSHIFT 8  // 256 nodes per bin

typedef __bf16 bf16x8 __attribute__((ext_vector_type(8)));
typedef float f32x4 __attribute__((ext_vector_type(4)));

static __device__ __forceinline__ unsigned short f2bf(float x) {
    unsigned int u = __builtin_bit_cast(unsigned int, x);
    unsigned int r = u + 0x7fffu + ((u >> 16) & 1u);
    return (unsigned short)(r >> 16);
}
static __device__ __forceinline__ float bitf(unsigned int u) {
    return __builtin_bit_cast(float, u);
}

// ---------------- K1: binA partition (blocks 0..127) || MFMA gemm w/ self-transpose ----------------
__global__ __launch_bounds__(256) void k1_kernel(const int* __restrict__ ei,
                                                 const float* __restrict__ W,
                                                 const float* __restrict__ x,
                                                 unsigned int* __restrict__ counts,
                                                 unsigned int* __restrict__ binned,
                                                 unsigned short* __restrict__ hs, int n, int E) {
    __shared__ char smem[48 * 1024];
    int t = threadIdx.x;
    int bid = blockIdx.x;

    if (bid < NBLK_A) {
        // ---- binA: partition edges into dst-bins (packed dst<<16|src) ----
        unsigned int* hist = (unsigned int*)smem;
        hist[t] = 0u;
        __syncthreads();
        int chunk = (E + NBLK_A - 1) / NBLK_A;
        int s0 = bid * chunk, s1 = min(E, s0 + chunk);
        const int* dstp = ei + E;
        for (int e = s0 + t; e < s1; e += 256) atomicAdd(&hist[dstp[e] >> BINSHIFT], 1u);
        __syncthreads();
        counts[bid * 256 + t] = hist[t];
        __syncthreads();
        hist[t] = 0u;
        __syncthreads();
        for (int e = s0 + t; e < s1; e += 256) {
            int src = ei[e];
            int d = dstp[e];
            int bin = d >> BINSHIFT;
            unsigned int off = atomicAdd(&hist[bin], 1u);
            binned[((unsigned)bin * NBLK_A + (unsigned)bid) * SUBCAP + off] =
                ((unsigned)d << 16) | (unsigned)src;
        }
        return;
    }

    // ---- MFMA gemm: hs = bf16(X*W), unscaled; W transposed+cast in-block ----
    uint4* Xs = (uint4*)smem;         // 64*16  = 16 KB
    uint4* Ws = (uint4*)smem + 1024;  // 128*16 = 32 KB
    int rowbase = (bid - NBLK_A) * 64;

    for (int cell = t; cell < 2048; cell += 256) {
        int nc = cell >> 4, s = cell & 15;
        const float* col = W + (s * 8) * 128 + nc;
        unsigned int a0 = f2bf(col[0]) | ((unsigned)f2bf(col[128]) << 16);
        unsigned int a1 = f2bf(col[256]) | ((unsigned)f2bf(col[384]) << 16);
        unsigned int a2 = f2bf(col[512]) | ((unsigned)f2bf(col[640]) << 16);
        unsigned int a3 = f2bf(col[768]) | ((unsigned)f2bf(col[896]) << 16);
        Ws[nc * 16 + (s ^ (nc & 7))] = make_uint4(a0, a1, a2, a3);
    }
    const float4* x4 = (const float4*)x;
#pragma unroll
    for (int j = 0; j < 4; ++j) {
        int gi = t + j * 256;
        int r = gi >> 4, s = gi & 15;
        uint4 v = make_uint4(0u, 0u, 0u, 0u);
        int grow = rowbase + r;
        if (grow < n) {
            float4 f0 = x4[(size_t)grow * 32 + s * 2];
            float4 f1 = x4[(size_t)grow * 32 + s * 2 + 1];
            v.x = f2bf(f0.x) | ((unsigned)f2bf(f0.y) << 16);
            v.y = f2bf(f0.z) | ((unsigned)f2bf(f0.w) << 16);
            v.z = f2bf(f1.x) | ((unsigned)f2bf(f1.y) << 16);
            v.w = f2bf(f1.z) | ((unsigned)f2bf(f1.w) << 16);
        }
        Xs[r * 16 + (s ^ (r & 7))] = v;
    }
    __syncthreads();

    int w = t >> 6, l = t & 63;
    int lr = l & 15, lg = l >> 4;
    f32x4 acc[4][2] = {};

#pragma unroll
    for (int kt = 0; kt < 4; ++kt) {
        int ks = kt * 4 + lg;
        bf16x8 bfr[2];
#pragma unroll
        for (int ct = 0; ct < 2; ++ct) {
            int nc = w * 32 + ct * 16 + lr;
            bfr[ct] = __builtin_bit_cast(bf16x8, Ws[nc * 16 + (ks ^ (nc & 7))]);
        }
#pragma unroll
        for (int mt = 0; mt < 4; ++mt) {
            int mr = mt * 16 + lr;
            bf16x8 afr = __builtin_bit_cast(bf16x8, Xs[mr * 16 + (ks ^ (mr & 7))]);
            acc[mt][0] = __builtin_amdgcn_mfma_f32_16x16x32_bf16(afr, bfr[0], acc[mt][0], 0, 0, 0);
            acc[mt][1] = __builtin_amdgcn_mfma_f32_16x16x32_bf16(afr, bfr[1], acc[mt][1], 0, 0, 0);
        }
    }

#pragma unroll
    for (int mt = 0; mt < 4; ++mt) {
        int row0 = rowbase + mt * 16 + lg * 4;
#pragma unroll
        for (int r = 0; r < 4; ++r) {
            int grow = row0 + r;
            if (grow < n) {
#pragma unroll
                for (int ct = 0; ct < 2; ++ct) {
                    int col = w * 32 + ct * 16 + lr;
                    hs[(size_t)grow * 128 + col] = f2bf(acc[mt][ct][r]);
                }
            }
        }
    }
}

// ---------------- K2: binB per-bin bucketization, LDS degree counters ----------------
__global__ __launch_bounds__(256) void k2_kernel(const unsigned int* __restrict__ counts,
                                                 const unsigned int* __restrict__ binned,
                                                 unsigned int* __restrict__ cnt,
                                                 float* __restrict__ disf,
                                                 unsigned short* __restrict__ bucket, int n) {
    __shared__ unsigned int lcnt[256];
    int t = threadIdx.x;
    int b = blockIdx.x;
    lcnt[t] = 0u;
    __syncthreads();
    int wv = t >> 6, ln = t & 63;
    for (int k = wv; k < NBLK_A; k += 4) {
        int m = (int)counts[k * 256 + b];
        unsigned int base = ((unsigned)b * NBLK_A + (unsigned)k) * SUBCAP;
        for (int i = ln; i < m; i += 64) {
            unsigned int p = binned[base + i];
            unsigned int d = p >> 16;
            unsigned int src = p & 0xffffu;
            unsigned int slot = atomicAdd(&lcnt[d & 255u], 1u);
            bucket[(size_t)d * CAP + (slot & (CAP - 1))] = (unsigned short)src;
        }
    }
    __syncthreads();
    int node = (b << BINSHIFT) + t;
    if (node < n) {
        unsigned int c = lcnt[t];
        cnt[node] = c;
        disf[node] = rsqrtf((float)c + 1.0f);
    }
}

#define ACC8F(A0, A1, U, DS)                    \
    do {                                        \
        A0.x += bitf((U).x << 16) * DS;         \
        A0.y += bitf((U).x & 0xffff0000u) * DS; \
        A0.z += bitf((U).y << 16) * DS;         \
        A0.w += bitf((U).y & 0xffff0000u) * DS; \
        A1.x += bitf((U).z << 16) * DS;         \
        A1.y += bitf((U).z & 0xffff0000u) * DS; \
        A1.z += bitf((U).w << 16) * DS;         \
        A1.w += bitf((U).w & 0xffff0000u) * DS; \
    } while (0)

// ---------------- K3 gather: out = dn*(sum h[s]*disf[s] + h[node]*dn) + b ----------------
__global__ __launch_bounds__(256) void gather_kernel(const unsigned short* __restrict__ bucket,
                                                     const unsigned int* __restrict__ cnt,
                                                     const float* __restrict__ disf,
                                                     const unsigned short* __restrict__ hs,
                                                     const float* __restrict__ b,
                                                     float* __restrict__ out, int n) {
    int node = (blockIdx.x * 256 + threadIdx.x) >> 4;
    int l = threadIdx.x & 15;
    if (node >= n) return;
    unsigned int c = cnt[node];
    float dn = disf[node];
    const unsigned short* seg = bucket + (size_t)node * CAP;
    const uint4* h4 = (const uint4*)hs;  // 16B = 8 bf16; row = 16 uint4

    uint4 u = h4[(size_t)node * 16 + l];  // self-loop: h[node]*dn
    float4 aA0 = make_float4(bitf(u.x << 16) * dn, bitf(u.x & 0xffff0000u) * dn,
                             bitf(u.y << 16) * dn, bitf(u.y & 0xffff0000u) * dn);
    float4 aA1 = make_float4(bitf(u.z << 16) * dn, bitf(u.z & 0xffff0000u) * dn,
                             bitf(u.w << 16) * dn, bitf(u.w & 0xffff0000u) * dn);
    float4 aB0 = make_float4(0.f, 0.f, 0.f, 0.f);
    float4 aB1 = make_float4(0.f, 0.f, 0.f, 0.f);

    for (unsigned int base = 0; base < c; base += 16) {
        int m = min(16u, c - base);
        int v = 0;
        float dv = 0.f;
        if (l < m) {
            v = (int)seg[base + l];
            dv = disf[v];
        }
        int j = 0;
        for (; j + 3 < m; j += 4) {
            int s0 = __shfl(v, j, 16);
            int s1 = __shfl(v, j + 1, 16);
            int s2 = __shfl(v, j + 2, 16);
            int s3 = __shfl(v, j + 3, 16);
            float d0 = __shfl(dv, j, 16);
            float d1 = __shfl(dv, j + 1, 16);
            float d2 = __shfl(dv, j + 2, 16);
            float d3 = __shfl(dv, j + 3, 16);
            uint4 u0 = h4[(size_t)s0 * 16 + l];
            uint4 u1 = h4[(size_t)s1 * 16 + l];
            uint4 u2 = h4[(size_t)s2 * 16 + l];
            uint4 u3 = h4[(size_t)s3 * 16 + l];
            ACC8F(aA0, aA1, u0, d0);
            ACC8F(aB0, aB1, u1, d1);
            ACC8F(aA0, aA1, u2, d2);
            ACC8F(aB0, aB1, u3, d3);
        }
        for (; j < m; ++j) {
            int s0 = __shfl(v, j, 16);
            float d0 = __shfl(dv, j, 16);
            uint4 u0 = h4[(size_t)s0 * 16 + l];
            ACC8F(aA0, aA1, u0, d0);
        }
    }

    float4 bv0 = ((const float4*)b)[l * 2];
    float4 bv1 = ((const float4*)b)[l * 2 + 1];
    float4 r0 = make_float4((aA0.x + aB0.x) * dn + bv0.x, (aA0.y + aB0.y) * dn + bv0.y,
                            (aA0.z + aB0.z) * dn + bv0.z, (aA0.w + aB0.w) * dn + bv0.w);
    float4 r1 = make_float4((aA1.x + aB1.x) * dn + bv1.x, (aA1.y + aB1.y) * dn + bv1.y,
                            (aA1.z + aB1.z) * dn + bv1.z, (aA1.w + aB1.w) * dn + bv1.w);
    float4* o4 = (float4*)out;
    o4[(size_t)node * 32 + l * 2] = r0;
    o4[(size_t)node * 32 + l * 2 + 1] = r1;
}

extern "C" void kernel_launch(void* const* d_in, const int* in_sizes, int n_in,
                              void* d_out, int out_size, void* d_ws, size_t ws_size,
                              hipStream_t stream) {
    const float* x = (const float*)d_in[0];
    const int* ei = (const int*)d_in[1];  // [2, E] int32
    const float* W = (const float*)d_in[2];
    const float* b = (const float*)d_in[3];
    float* out = (float*)d_out;

    int n = in_sizes[0] / D;  // 50000
    int E = in_sizes[1] / 2;  // 600000
    int NB = (n + 255) >> 8;  // 196 bins of 256 nodes

    unsigned int* counts = (unsigned int*)d_ws;        // NBLK_A*256
    unsigned int* cnt = counts + NBLK_A * 256;         // n
    float* disf = (float*)(cnt + n);                   // n
    unsigned int* binned = (unsigned int*)(disf + n);  // NB*NBLK_A*SUBCAP
    unsigned short* bucket = (unsigned short*)(binned + (size_t)NB * NBLK_A * SUBCAP);  // n*CAP
    unsigned short* hs = bucket + (size_t)n * CAP;     // n*D

    k1_kernel<<<NBLK_A + (n + 63) / 64, 256, 0, stream>>>(ei, W, x, counts, binned, hs, n, E);
    k2_kernel<<<NB, 256, 0, stream>>>(counts, binned, cnt, disf, bucket, n);
    gather_kernel<<<(n * 16 + 255) / 256, 256, 0, stream>>>(bucket, cnt, disf, hs, b, out, n);
}

// Round 16
// 73.970 us; speedup vs baseline: 2.7174x; 1.2749x over previous
//
#include <hip/hip_runtime.h>

#define D 128
#define CAP 64      // per-node bucket capacity (max degree ~35 for Poisson(12))
#define NBLK_A 128  // binA partition blocks
#define SUBCAP 64   // per-(block,bin) segment capacity
#define BINSHIFT 8  // 256 nodes per bin

typedef __bf16 bf16x8 __attribute__((ext_vector_type(8)));
typedef float f32x4 __attribute__((ext_vector_type(4)));

static __device__ __forceinline__ unsigned short f2bf(float x) {
    unsigned int u = __builtin_bit_cast(unsigned int, x);
    unsigned int r = u + 0x7fffu + ((u >> 16) & 1u);
    return (unsigned short)(r >> 16);
}
static __device__ __forceinline__ float bitf(unsigned int u) {
    return __builtin_bit_cast(float, u);
}

// ---------------- K1: binA partition (blocks 0..127) + W transpose (blocks 128..135) ----------------
__global__ __launch_bounds__(256) void k1_kernel(const int* __restrict__ ei,
                                                 const float* __restrict__ W,
                                                 unsigned int* __restrict__ counts,
                                                 unsigned int* __restrict__ binned,
                                                 unsigned short* __restrict__ wt, int E) {
    int t = threadIdx.x;
    int k = blockIdx.x;
    if (k < NBLK_A) {
        __shared__ unsigned int hist[256];
        hist[t] = 0u;
        __syncthreads();
        int chunk = (E + NBLK_A - 1) / NBLK_A;
        int s0 = k * chunk, s1 = min(E, s0 + chunk);
        const int* dstp = ei + E;
        for (int e = s0 + t; e < s1; e += 256) atomicAdd(&hist[dstp[e] >> BINSHIFT], 1u);
        __syncthreads();
        counts[k * 256 + t] = hist[t];
        __syncthreads();
        hist[t] = 0u;
        __syncthreads();
        for (int e = s0 + t; e < s1; e += 256) {
            int src = ei[e];
            int d = dstp[e];
            int bin = d >> BINSHIFT;
            unsigned int off = atomicAdd(&hist[bin], 1u);
            binned[((unsigned)bin * NBLK_A + (unsigned)k) * SUBCAP + off] =
                ((unsigned)d << 16) | (unsigned)src;
        }
    } else {
        int tid = (k - NBLK_A) * 256 + t;  // 8 blocks -> 2048 threads
        for (int i = tid; i < D * D; i += 8 * 256) {
            int r = i >> 7, c = i & 127;
            wt[c * 128 + r] = f2bf(W[i]);
        }
    }
}

// ---------------- K2: binB bucketize (blocks 0..NB-1) || MFMA gemm (rest) ----------------
__global__ __launch_bounds__(256) void k2_kernel(const unsigned int* __restrict__ counts,
                                                 const unsigned int* __restrict__ binned,
                                                 const float* __restrict__ x,
                                                 const unsigned short* __restrict__ wt,
                                                 unsigned int* __restrict__ cnt,
                                                 float* __restrict__ disf,
                                                 unsigned short* __restrict__ bucket,
                                                 unsigned short* __restrict__ hs, int n, int NB) {
    __shared__ char smem[48 * 1024];
    int t = threadIdx.x;
    int bid = blockIdx.x;

    if (bid < NB) {
        unsigned int* lcnt = (unsigned int*)smem;
        lcnt[t] = 0u;
        __syncthreads();
        int wv = t >> 6, ln = t & 63;
        int b = bid;
        for (int k = wv; k < NBLK_A; k += 4) {
            int m = (int)counts[k * 256 + b];
            unsigned int base = ((unsigned)b * NBLK_A + (unsigned)k) * SUBCAP;
            for (int i = ln; i < m; i += 64) {
                unsigned int p = binned[base + i];
                unsigned int d = p >> 16;
                unsigned int src = p & 0xffffu;
                unsigned int slot = atomicAdd(&lcnt[d & 255u], 1u);
                bucket[(size_t)d * CAP + (slot & (CAP - 1))] = (unsigned short)src;
            }
        }
        __syncthreads();
        int node = (b << BINSHIFT) + t;
        if (node < n) {
            unsigned int c = lcnt[t];
            cnt[node] = c;
            disf[node] = rsqrtf((float)c + 1.0f);
        }
        return;
    }

    // ---- MFMA gemm: hs = bf16(X*W), unscaled ----
    uint4* Xs = (uint4*)smem;         // 16 KB
    uint4* Ws = (uint4*)smem + 1024;  // 32 KB
    int rowbase = (bid - NB) * 64;

    const uint4* wg = (const uint4*)wt;
#pragma unroll
    for (int j = 0; j < 8; ++j) {
        int gi = t + j * 256;
        int r = gi >> 4, s = gi & 15;
        Ws[r * 16 + (s ^ (r & 7))] = wg[gi];
    }
    const float4* x4 = (const float4*)x;
#pragma unroll
    for (int j = 0; j < 4; ++j) {
        int gi = t + j * 256;
        int r = gi >> 4, s = gi & 15;
        uint4 v = make_uint4(0u, 0u, 0u, 0u);
        int grow = rowbase + r;
        if (grow < n) {
            float4 f0 = x4[(size_t)grow * 32 + s * 2];
            float4 f1 = x4[(size_t)grow * 32 + s * 2 + 1];
            v.x = f2bf(f0.x) | ((unsigned)f2bf(f0.y) << 16);
            v.y = f2bf(f0.z) | ((unsigned)f2bf(f0.w) << 16);
            v.z = f2bf(f1.x) | ((unsigned)f2bf(f1.y) << 16);
            v.w = f2bf(f1.z) | ((unsigned)f2bf(f1.w) << 16);
        }
        Xs[r * 16 + (s ^ (r & 7))] = v;
    }
    __syncthreads();

    int w = t >> 6, l = t & 63;
    int lr = l & 15, lg = l >> 4;
    f32x4 acc[4][2] = {};

#pragma unroll
    for (int kt = 0; kt < 4; ++kt) {
        int ks = kt * 4 + lg;
        bf16x8 bfr[2];
#pragma unroll
        for (int ct = 0; ct < 2; ++ct) {
            int nc = w * 32 + ct * 16 + lr;
            bfr[ct] = __builtin_bit_cast(bf16x8, Ws[nc * 16 + (ks ^ (nc & 7))]);
        }
#pragma unroll
        for (int mt = 0; mt < 4; ++mt) {
            int mr = mt * 16 + lr;
            bf16x8 afr = __builtin_bit_cast(bf16x8, Xs[mr * 16 + (ks ^ (mr & 7))]);
            acc[mt][0] = __builtin_amdgcn_mfma_f32_16x16x32_bf16(afr, bfr[0], acc[mt][0], 0, 0, 0);
            acc[mt][1] = __builtin_amdgcn_mfma_f32_16x16x32_bf16(afr, bfr[1], acc[mt][1], 0, 0, 0);
        }
    }

#pragma unroll
    for (int mt = 0; mt < 4; ++mt) {
        int row0 = rowbase + mt * 16 + lg * 4;
#pragma unroll
        for (int r = 0; r < 4; ++r) {
            int grow = row0 + r;
            if (grow < n) {
#pragma unroll
                for (int ct = 0; ct < 2; ++ct) {
                    int col = w * 32 + ct * 16 + lr;
                    hs[(size_t)grow * 128 + col] = f2bf(acc[mt][ct][r]);
                }
            }
        }
    }
}

#define ACC8F(A0, A1, U, DS)                    \
    do {                                        \
        A0.x += bitf((U).x << 16) * DS;         \
        A0.y += bitf((U).x & 0xffff0000u) * DS; \
        A0.z += bitf((U).y << 16) * DS;         \
        A0.w += bitf((U).y & 0xffff0000u) * DS; \
        A1.x += bitf((U).z << 16) * DS;         \
        A1.y += bitf((U).z & 0xffff0000u) * DS; \
        A1.z += bitf((U).w << 16) * DS;         \
        A1.w += bitf((U).w & 0xffff0000u) * DS; \
    } while (0)

// ---------------- K3 gather: out = dn*(sum h[s]*disf[s] + h[node]*dn) + b ----------------
// 16 lanes/node, uint4 loads, 8-wide unrolled (8 loads in flight, 2 acc banks).
__global__ __launch_bounds__(256) void gather_kernel(const unsigned short* __restrict__ bucket,
                                                     const unsigned int* __restrict__ cnt,
                                                     const float* __restrict__ disf,
                                                     const unsigned short* __restrict__ hs,
                                                     const float* __restrict__ b,
                                                     float* __restrict__ out, int n) {
    int node = (blockIdx.x * 256 + threadIdx.x) >> 4;
    int l = threadIdx.x & 15;
    if (node >= n) return;
    unsigned int c = cnt[node];
    float dn = disf[node];
    const unsigned short* seg = bucket + (size_t)node * CAP;
    const uint4* h4 = (const uint4*)hs;  // 16B = 8 bf16; row = 16 uint4

    uint4 u = h4[(size_t)node * 16 + l];  // self-loop: h[node]*dn
    float4 aA0 = make_float4(bitf(u.x << 16) * dn, bitf(u.x & 0xffff0000u) * dn,
                             bitf(u.y << 16) * dn, bitf(u.y & 0xffff0000u) * dn);
    float4 aA1 = make_float4(bitf(u.z << 16) * dn, bitf(u.z & 0xffff0000u) * dn,
                             bitf(u.w << 16) * dn, bitf(u.w & 0xffff0000u) * dn);
    float4 aB0 = make_float4(0.f, 0.f, 0.f, 0.f);
    float4 aB1 = make_float4(0.f, 0.f, 0.f, 0.f);

    for (unsigned int base = 0; base < c; base += 16) {
        int m = min(16u, c - base);
        int v = 0;
        float dv = 0.f;
        if (l < m) {
            v = (int)seg[base + l];
            dv = disf[v];
        }
        int j = 0;
        for (; j + 7 < m; j += 8) {
            int s0 = __shfl(v, j, 16);
            int s1 = __shfl(v, j + 1, 16);
            int s2 = __shfl(v, j + 2, 16);
            int s3 = __shfl(v, j + 3, 16);
            int s4 = __shfl(v, j + 4, 16);
            int s5 = __shfl(v, j + 5, 16);
            int s6 = __shfl(v, j + 6, 16);
            int s7 = __shfl(v, j + 7, 16);
            float d0 = __shfl(dv, j, 16);
            float d1 = __shfl(dv, j + 1, 16);
            float d2 = __shfl(dv, j + 2, 16);
            float d3 = __shfl(dv, j + 3, 16);
            float d4 = __shfl(dv, j + 4, 16);
            float d5 = __shfl(dv, j + 5, 16);
            float d6 = __shfl(dv, j + 6, 16);
            float d7 = __shfl(dv, j + 7, 16);
            uint4 u0 = h4[(size_t)s0 * 16 + l];
            uint4 u1 = h4[(size_t)s1 * 16 + l];
            uint4 u2 = h4[(size_t)s2 * 16 + l];
            uint4 u3 = h4[(size_t)s3 * 16 + l];
            uint4 u4 = h4[(size_t)s4 * 16 + l];
            uint4 u5 = h4[(size_t)s5 * 16 + l];
            uint4 u6 = h4[(size_t)s6 * 16 + l];
            uint4 u7 = h4[(size_t)s7 * 16 + l];
            ACC8F(aA0, aA1, u0, d0);
            ACC8F(aB0, aB1, u1, d1);
            ACC8F(aA0, aA1, u2, d2);
            ACC8F(aB0, aB1, u3, d3);
            ACC8F(aA0, aA1, u4, d4);
            ACC8F(aB0, aB1, u5, d5);
            ACC8F(aA0, aA1, u6, d6);
            ACC8F(aB0, aB1, u7, d7);
        }
        for (; j < m; ++j) {
            int s0 = __shfl(v, j, 16);
            float d0 = __shfl(dv, j, 16);
            uint4 u0 = h4[(size_t)s0 * 16 + l];
            ACC8F(aA0, aA1, u0, d0);
        }
    }

    float4 bv0 = ((const float4*)b)[l * 2];
    float4 bv1 = ((const float4*)b)[l * 2 + 1];
    float4 r0 = make_float4((aA0.x + aB0.x) * dn + bv0.x, (aA0.y + aB0.y) * dn + bv0.y,
                            (aA0.z + aB0.z) * dn + bv0.z, (aA0.w + aB0.w) * dn + bv0.w);
    float4 r1 = make_float4((aA1.x + aB1.x) * dn + bv1.x, (aA1.y + aB1.y) * dn + bv1.y,
                            (aA1.z + aB1.z) * dn + bv1.z, (aA1.w + aB1.w) * dn + bv1.w);
    float4* o4 = (float4*)out;
    o4[(size_t)node * 32 + l * 2] = r0;
    o4[(size_t)node * 32 + l * 2 + 1] = r1;
}

extern "C" void kernel_launch(void* const* d_in, const int* in_sizes, int n_in,
                              void* d_out, int out_size, void* d_ws, size_t ws_size,
                              hipStream_t stream) {
    const float* x = (const float*)d_in[0];
    const int* ei = (const int*)d_in[1];  // [2, E] int32
    const float* W = (const float*)d_in[2];
    const float* b = (const float*)d_in[3];
    float* out = (float*)d_out;

    int n = in_sizes[0] / D;  // 50000
    int E = in_sizes[1] / 2;  // 600000
    int NB = (n + 255) >> 8;  // 196 bins of 256 nodes

    unsigned int* counts = (unsigned int*)d_ws;        // NBLK_A*256
    unsigned int* cnt = counts + NBLK_A * 256;         // n
    float* disf = (float*)(cnt + n);                   // n
    unsigned int* binned = (unsigned int*)(disf + n);  // NB*NBLK_A*SUBCAP
    unsigned short* bucket = (unsigned short*)(binned + (size_t)NB * NBLK_A * SUBCAP);  // n*CAP
    unsigned short* hs = bucket + (size_t)n * CAP;     // n*D bf16
    unsigned short* wt = hs + (size_t)n * D;           // D*D

    k1_kernel<<<NBLK_A + 8, 256, 0, stream>>>(ei, W, counts, binned, wt, E);
    k2_kernel<<<NB + (n + 63) / 64, 256, 0, stream>>>(counts, binned, x, wt, cnt, disf, bucket,
                                                      hs, n, NB);
    gather_kernel<<<(n * 16 + 255) / 256, 256, 0, stream>>>(bucket, cnt, disf, hs, b, out, n);
}

// Round 17
// 70.054 us; speedup vs baseline: 2.8692x; 1.0559x over previous
//
#include <hip/hip_runtime.h>

#define D 128
#define CAP 64      // per-node bucket capacity (max degree ~35 for Poisson(12))
#define NBLK_A 128  // binA partition blocks
#define SUBCAP 64   // per-(block,bin) segment capacity
#define BINSHIFT 8  // 256 nodes per bin

typedef __bf16 bf16x8 __attribute__((ext_vector_type(8)));
typedef float f32x4 __attribute__((ext_vector_type(4)));

static __device__ __forceinline__ unsigned short f2bf(float x) {
    unsigned int u = __builtin_bit_cast(unsigned int, x);
    unsigned int r = u + 0x7fffu + ((u >> 16) & 1u);
    return (unsigned short)(r >> 16);
}
static __device__ __forceinline__ float bitf(unsigned int u) {
    return __builtin_bit_cast(float, u);
}

// ---------------- K1: binA partition (blocks 0..127) + W transpose (blocks 128..135) ----------------
__global__ __launch_bounds__(256) void k1_kernel(const int* __restrict__ ei,
                                                 const float* __restrict__ W,
                                                 unsigned int* __restrict__ counts,
                                                 unsigned int* __restrict__ binned,
                                                 unsigned short* __restrict__ wt, int E) {
    int t = threadIdx.x;
    int k = blockIdx.x;
    if (k < NBLK_A) {
        __shared__ unsigned int hist[256];
        hist[t] = 0u;
        __syncthreads();
        int chunk = (E + NBLK_A - 1) / NBLK_A;
        int s0 = k * chunk, s1 = min(E, s0 + chunk);
        const int* dstp = ei + E;
        for (int e = s0 + t; e < s1; e += 256) atomicAdd(&hist[dstp[e] >> BINSHIFT], 1u);
        __syncthreads();
        counts[k * 256 + t] = hist[t];
        __syncthreads();
        hist[t] = 0u;
        __syncthreads();
        for (int e = s0 + t; e < s1; e += 256) {
            int src = ei[e];
            int d = dstp[e];
            int bin = d >> BINSHIFT;
            unsigned int off = atomicAdd(&hist[bin], 1u);
            binned[((unsigned)bin * NBLK_A + (unsigned)k) * SUBCAP + off] =
                ((unsigned)d << 16) | (unsigned)src;
        }
    } else {
        int tid = (k - NBLK_A) * 256 + t;  // 8 blocks -> 2048 threads
        for (int i = tid; i < D * D; i += 8 * 256) {
            int r = i >> 7, c = i & 127;
            wt[c * 128 + r] = f2bf(W[i]);
        }
    }
}

// ---------------- K2: binB bucketize (blocks 0..NB-1) || MFMA gemm (rest) ----------------
__global__ __launch_bounds__(256) void k2_kernel(const unsigned int* __restrict__ counts,
                                                 const unsigned int* __restrict__ binned,
                                                 const float* __restrict__ x,
                                                 const unsigned short* __restrict__ wt,
                                                 unsigned int* __restrict__ cnt,
                                                 float* __restrict__ disf,
                                                 unsigned short* __restrict__ bucket,
                                                 unsigned short* __restrict__ hs, int n, int NB) {
    __shared__ char smem[48 * 1024];
    int t = threadIdx.x;
    int bid = blockIdx.x;

    if (bid < NB) {
        unsigned int* lcnt = (unsigned int*)smem;
        lcnt[t] = 0u;
        __syncthreads();
        int wv = t >> 6, ln = t & 63;
        int b = bid;
        for (int k = wv; k < NBLK_A; k += 4) {
            int m = (int)counts[k * 256 + b];
            unsigned int base = ((unsigned)b * NBLK_A + (unsigned)k) * SUBCAP;
            for (int i = ln; i < m; i += 64) {
                unsigned int p = binned[base + i];
                unsigned int d = p >> 16;
                unsigned int src = p & 0xffffu;
                unsigned int slot = atomicAdd(&lcnt[d & 255u], 1u);
                bucket[(size_t)d * CAP + (slot & (CAP - 1))] = (unsigned short)src;
            }
        }
        __syncthreads();
        int node = (b << BINSHIFT) + t;
        if (node < n) {
            unsigned int c = lcnt[t];
            cnt[node] = c;
            disf[node] = rsqrtf((float)c + 1.0f);
        }
        return;
    }

    // ---- MFMA gemm: hs = bf16(X*W), unscaled ----
    uint4* Xs = (uint4*)smem;         // 16 KB
    uint4* Ws = (uint4*)smem + 1024;  // 32 KB
    int rowbase = (bid - NB) * 64;

    const uint4* wg = (const uint4*)wt;
#pragma unroll
    for (int j = 0; j < 8; ++j) {
        int gi = t + j * 256;
        int r = gi >> 4, s = gi & 15;
        Ws[r * 16 + (s ^ (r & 7))] = wg[gi];
    }
    const float4* x4 = (const float4*)x;
#pragma unroll
    for (int j = 0; j < 4; ++j) {
        int gi = t + j * 256;
        int r = gi >> 4, s = gi & 15;
        uint4 v = make_uint4(0u, 0u, 0u, 0u);
        int grow = rowbase + r;
        if (grow < n) {
            float4 f0 = x4[(size_t)grow * 32 + s * 2];
            float4 f1 = x4[(size_t)grow * 32 + s * 2 + 1];
            v.x = f2bf(f0.x) | ((unsigned)f2bf(f0.y) << 16);
            v.y = f2bf(f0.z) | ((unsigned)f2bf(f0.w) << 16);
            v.z = f2bf(f1.x) | ((unsigned)f2bf(f1.y) << 16);
            v.w = f2bf(f1.z) | ((unsigned)f2bf(f1.w) << 16);
        }
        Xs[r * 16 + (s ^ (r & 7))] = v;
    }
    __syncthreads();

    int w = t >> 6, l = t & 63;
    int lr = l & 15, lg = l >> 4;
    f32x4 acc[4][2] = {};

#pragma unroll
    for (int kt = 0; kt < 4; ++kt) {
        int ks = kt * 4 + lg;
        bf16x8 bfr[2];
#pragma unroll
        for (int ct = 0; ct < 2; ++ct) {
            int nc = w * 32 + ct * 16 + lr;
            bfr[ct] = __builtin_bit_cast(bf16x8, Ws[nc * 16 + (ks ^ (nc & 7))]);
        }
#pragma unroll
        for (int mt = 0; mt < 4; ++mt) {
            int mr = mt * 16 + lr;
            bf16x8 afr = __builtin_bit_cast(bf16x8, Xs[mr * 16 + (ks ^ (mr & 7))]);
            acc[mt][0] = __builtin_amdgcn_mfma_f32_16x16x32_bf16(afr, bfr[0], acc[mt][0], 0, 0, 0);
            acc[mt][1] = __builtin_amdgcn_mfma_f32_16x16x32_bf16(afr, bfr[1], acc[mt][1], 0, 0, 0);
        }
    }

#pragma unroll
    for (int mt = 0; mt < 4; ++mt) {
        int row0 = rowbase + mt * 16 + lg * 4;
#pragma unroll
        for (int r = 0; r < 4; ++r) {
            int grow = row0 + r;
            if (grow < n) {
#pragma unroll
                for (int ct = 0; ct < 2; ++ct) {
                    int col = w * 32 + ct * 16 + lr;
                    hs[(size_t)grow * 128 + col] = f2bf(acc[mt][ct][r]);
                }
            }
        }
    }
}

#define ACC8F(A0, A1, U, DS)                    \
    do {                                        \
        A0.x += bitf((U).x << 16) * DS;         \
        A0.y += bitf((U).x & 0xffff0000u) * DS; \
        A0.z += bitf((U).y << 16) * DS;         \
        A0.w += bitf((U).y & 0xffff0000u) * DS; \
        A1.x += bitf((U).z << 16) * DS;         \
        A1.y += bitf((U).z & 0xffff0000u) * DS; \
        A1.z += bitf((U).w << 16) * DS;         \
        A1.w += bitf((U).w & 0xffff0000u) * DS; \
    } while (0)

// ---------------- K3 gather: out = dn*(sum h[s]*disf[s] + h[node]*dn) + b ----------------
// 16 lanes/node, uint4 loads, 4-wide unrolled (empirical optimum, R11).
__global__ __launch_bounds__(256) void gather_kernel(const unsigned short* __restrict__ bucket,
                                                     const unsigned int* __restrict__ cnt,
                                                     const float* __restrict__ disf,
                                                     const unsigned short* __restrict__ hs,
                                                     const float* __restrict__ b,
                                                     float* __restrict__ out, int n) {
    int node = (blockIdx.x * 256 + threadIdx.x) >> 4;
    int l = threadIdx.x & 15;
    if (node >= n) return;
    unsigned int c = cnt[node];
    float dn = disf[node];
    const unsigned short* seg = bucket + (size_t)node * CAP;
    const uint4* h4 = (const uint4*)hs;  // 16B = 8 bf16; row = 16 uint4

    uint4 u = h4[(size_t)node * 16 + l];  // self-loop: h[node]*dn
    float4 aA0 = make_float4(bitf(u.x << 16) * dn, bitf(u.x & 0xffff0000u) * dn,
                             bitf(u.y << 16) * dn, bitf(u.y & 0xffff0000u) * dn);
    float4 aA1 = make_float4(bitf(u.z << 16) * dn, bitf(u.z & 0xffff0000u) * dn,
                             bitf(u.w << 16) * dn, bitf(u.w & 0xffff0000u) * dn);
    float4 aB0 = make_float4(0.f, 0.f, 0.f, 0.f);
    float4 aB1 = make_float4(0.f, 0.f, 0.f, 0.f);

    for (unsigned int base = 0; base < c; base += 16) {
        int m = min(16u, c - base);
        int v = 0;
        float dv = 0.f;
        if (l < m) {
            v = (int)seg[base + l];
            dv = disf[v];
        }
        int j = 0;
        for (; j + 3 < m; j += 4) {
            int s0 = __shfl(v, j, 16);
            int s1 = __shfl(v, j + 1, 16);
            int s2 = __shfl(v, j + 2, 16);
            int s3 = __shfl(v, j + 3, 16);
            float d0 = __shfl(dv, j, 16);
            float d1 = __shfl(dv, j + 1, 16);
            float d2 = __shfl(dv, j + 2, 16);
            float d3 = __shfl(dv, j + 3, 16);
            uint4 u0 = h4[(size_t)s0 * 16 + l];
            uint4 u1 = h4[(size_t)s1 * 16 + l];
            uint4 u2 = h4[(size_t)s2 * 16 + l];
            uint4 u3 = h4[(size_t)s3 * 16 + l];
            ACC8F(aA0, aA1, u0, d0);
            ACC8F(aB0, aB1, u1, d1);
            ACC8F(aA0, aA1, u2, d2);
            ACC8F(aB0, aB1, u3, d3);
        }
        for (; j < m; ++j) {
            int s0 = __shfl(v, j, 16);
            float d0 = __shfl(dv, j, 16);
            uint4 u0 = h4[(size_t)s0 * 16 + l];
            ACC8F(aA0, aA1, u0, d0);
        }
    }

    float4 bv0 = ((const float4*)b)[l * 2];
    float4 bv1 = ((const float4*)b)[l * 2 + 1];
    float4 r0 = make_float4((aA0.x + aB0.x) * dn + bv0.x, (aA0.y + aB0.y) * dn + bv0.y,
                            (aA0.z + aB0.z) * dn + bv0.z, (aA0.w + aB0.w) * dn + bv0.w);
    float4 r1 = make_float4((aA1.x + aB1.x) * dn + bv1.x, (aA1.y + aB1.y) * dn + bv1.y,
                            (aA1.z + aB1.z) * dn + bv1.z, (aA1.w + aB1.w) * dn + bv1.w);
    float4* o4 = (float4*)out;
    o4[(size_t)node * 32 + l * 2] = r0;
    o4[(size_t)node * 32 + l * 2 + 1] = r1;
}

extern "C" void kernel_launch(void* const* d_in, const int* in_sizes, int n_in,
                              void* d_out, int out_size, void* d_ws, size_t ws_size,
                              hipStream_t stream) {
    const float* x = (const float*)d_in[0];
    const int* ei = (const int*)d_in[1];  // [2, E] int32
    const float* W = (const float*)d_in[2];
    const float* b = (const float*)d_in[3];
    float* out = (float*)d_out;

    int n = in_sizes[0] / D;  // 50000
    int E = in_sizes[1] / 2;  // 600000
    int NB = (n + 255) >> 8;  // 196 bins of 256 nodes

    unsigned int* counts = (unsigned int*)d_ws;        // NBLK_A*256
    unsigned int* cnt = counts + NBLK_A * 256;         // n
    float* disf = (float*)(cnt + n);                   // n
    unsigned int* binned = (unsigned int*)(disf + n);  // NB*NBLK_A*SUBCAP
    unsigned short* bucket = (unsigned short*)(binned + (size_t)NB * NBLK_A * SUBCAP);  // n*CAP
    unsigned short* hs = bucket + (size_t)n * CAP;     // n*D bf16
    unsigned short* wt = hs + (size_t)n * D;           // D*D

    k1_kernel<<<NBLK_A + 8, 256, 0, stream>>>(ei, W, counts, binned, wt, E);
    k2_kernel<<<NB + (n + 63) / 64, 256, 0, stream>>>(counts, binned, x, wt, cnt, disf, bucket,
                                                      hs, n, NB);
    gather_kernel<<<(n * 16 + 255) / 256, 256, 0, stream>>>(bucket, cnt, disf, hs, b, out, n);
}